// Round 15
// baseline (216.203 us; speedup 1.0000x reference)
//
#include <hip/hip_runtime.h>
#include <stdint.h>

// GaussianKernelSimilarity: z[8192,1024] f32, expert_keys[4096,1024] f32
// out0 = exp(-max(|z|^2+|e|^2-2 z.e, 0)/2)  [8192,4096]
// out1 = softmax(out0, axis=-1) @ expert_keys [8192,1024]
//
// Round 15: persistent GEMM1. Evidence: GEMM1-lean(97us) vs GEMM2(50us) run
// the SAME 32768 block-iterations; the 2x gap is per-block fixed cost paid
// over 4 residency rounds (2048 blocks) vs 1 (512). Fix: 512 blocks, each
// processing its super-tile's 4 n-tiles sequentially; next tile's staging
// issued BEFORE the epilogue (HBM latency hides under epilogue); epilogue
// scratch in the free second LDS buffers. K-loop/epilogue math = r9/r14.
// GEMM2 = r14 (integrated rowsum reduce from rs_part in prologue).

#define M_TOK 8192
#define N_EXP 4096
#define D_DIM 1024

typedef __attribute__((ext_vector_type(4))) float f32x4;
typedef __attribute__((ext_vector_type(8))) short short8;
typedef __attribute__((ext_vector_type(4))) unsigned short u16x4;
typedef unsigned short u16;
typedef unsigned int u32;

__device__ __forceinline__ u16 f32_to_bf16(float f) {
  u32 u = __builtin_bit_cast(u32, f);
  u += 0x7fff + ((u >> 16) & 1);   // round-to-nearest-even
  return (u16)(u >> 16);
}

__device__ __forceinline__ void async16(const void* g, void* l) {
  __builtin_amdgcn_global_load_lds((__attribute__((address_space(1))) void*)(g),
                                   (__attribute__((address_space(3))) void*)(l),
                                   16, 0, 0);
}

// ---- prep: f32 -> bf16 convert + row |.|^2 for BOTH z and e (one launch) --
__global__ __launch_bounds__(256) void prep_convert2(const float* __restrict__ zsrc,
                                                     const float* __restrict__ esrc,
                                                     u16* __restrict__ zdst,
                                                     u16* __restrict__ edst,
                                                     float* __restrict__ zsq,
                                                     float* __restrict__ esq) {
  int row = blockIdx.x;
  const float* src;
  u16* dst;
  float* sq;
  if (row < M_TOK) {
    src = zsrc + (size_t)row * D_DIM;
    dst = zdst + (size_t)row * D_DIM;
    sq = zsq + row;
  } else {
    int r = row - M_TOK;
    src = esrc + (size_t)r * D_DIM;
    dst = edst + (size_t)r * D_DIM;
    sq = esq + r;
  }
  int t = threadIdx.x;                       // 256 threads, 4 elems each
  const float4 v = ((const float4*)src)[t];
  ushort4 h;
  h.x = f32_to_bf16(v.x); h.y = f32_to_bf16(v.y);
  h.z = f32_to_bf16(v.z); h.w = f32_to_bf16(v.w);
  ((ushort4*)dst)[t] = h;
  float p = v.x * v.x + v.y * v.y + v.z * v.z + v.w * v.w;
#pragma unroll
  for (int off = 1; off < 64; off <<= 1) p += __shfl_xor(p, off, 64);
  __shared__ float partial[4];
  if ((t & 63) == 0) partial[t >> 6] = p;
  __syncthreads();
  if (t == 0) *sq = partial[0] + partial[1] + partial[2] + partial[3];
}

// ---- bf16 transpose: eb[4096][1024] -> ebT[1024][4096] --------------------
__global__ __launch_bounds__(256) void transpose_bf16(const u16* __restrict__ src,
                                                      u16* __restrict__ dst) {
  __shared__ u16 tile[64][65];
  int e0 = blockIdx.x * 64;
  int d0 = blockIdx.y * 64;
  int t = threadIdx.x;
  int lr = t >> 4;
  int lc = (t & 15) * 4;
#pragma unroll
  for (int r8 = 0; r8 < 4; ++r8) {
    int row = lr + r8 * 16;
    ushort4 v = *(const ushort4*)(src + (size_t)(e0 + row) * D_DIM + d0 + lc);
    tile[row][lc + 0] = v.x; tile[row][lc + 1] = v.y;
    tile[row][lc + 2] = v.z; tile[row][lc + 3] = v.w;
  }
  __syncthreads();
#pragma unroll
  for (int r8 = 0; r8 < 4; ++r8) {
    int dl = lr + r8 * 16;
    ushort4 v;
    v.x = tile[lc + 0][dl]; v.y = tile[lc + 1][dl];
    v.z = tile[lc + 2][dl]; v.w = tile[lc + 3][dl];
    *(ushort4*)(dst + (size_t)(d0 + dl) * N_EXP + e0 + lc) = v;
  }
}

// ---- rowsum reduce (fallback path only) -----------------------------------
__global__ __launch_bounds__(256) void rowsum_reduce(const float* __restrict__ part,
                                                     float* __restrict__ rowsum) {
  int r = blockIdx.x * 256 + threadIdx.x;
  float s = 0.f;
#pragma unroll 8
  for (int j = 0; j < 128; ++j) s += part[(size_t)j * M_TOK + r];
  rowsum[r] = s;
}

// ---- gemm1_persist: GEMM1, 512 blocks x 4 sequential n-tiles --------------
// Per tile: K-loop (r9: BK=64, dbuf, XOR swizzle, swapped-operand MFMA),
// then issue NEXT tile's first staging into buf0 (both buffers free; nIter
// even so cur ends at 0), then epilogue with scratch in buf1 halves of
// smA/smB, then one barrier (drains staging + scratch).
// Epilogue = r14 EPI=1: sim=exp(-d2/2) -> nt full-line stores; es=exp(sim)
// once -> Wb + partial rowsum rs_part[slot][row] (no atomics).
__global__ __launch_bounds__(512, 4) void gemm1_persist(const u16* __restrict__ A,
                                                        const u16* __restrict__ Bt,
                                                        float* __restrict__ out,
                                                        const float* __restrict__ a_sq,
                                                        const float* __restrict__ b_sq,
                                                        float* __restrict__ rs_part,
                                                        u16* __restrict__ wb) {
  constexpr int BM = 128, BN = 128, BK = 64;
  constexpr int Kdim = D_DIM, ldo = N_EXP, nIter = Kdim / BK;  // 16 (even)
  __shared__ __align__(16) u16 smA[2 * BM * BK];   // 32 KiB
  __shared__ __align__(16) u16 smB[2 * BN * BK];   // 32 KiB

  const int wg = blockIdx.x;       // 0..511
  const int xcd = wg & 7;
  const int idx = wg >> 3;         // 0..63
  const int sup = idx >> 3;        // 0..7  n-group
  const int mloc = idx & 7;        // 0..7
  const int m0 = (xcd * 8 + mloc) * BM;

  const int t = threadIdx.x;
  const int l = t & 63;
  const int w = t >> 6;            // wave 0..7
  const int wr = w >> 2;           // 0..1 (M)
  const int wc = w & 3;            // 0..3 (N)
  const int lr8 = l >> 3;
  const int cswz = (((l & 7) ^ lr8) << 3);
  const int s0 = w * 2, s1 = w * 2 + 1;
  const int str0 = s0 * 8 + lr8, str1 = s1 * 8 + lr8;

#define STAGE1(n0_, kelem, bufb) do { \
    async16(A + (size_t)(m0 + str0) * Kdim + (kelem) + cswz, smA + (bufb) + s0 * 512); \
    async16(A + (size_t)(m0 + str1) * Kdim + (kelem) + cswz, smA + (bufb) + s1 * 512); \
    async16(Bt + (size_t)((n0_) + str0) * Kdim + (kelem) + cswz, smB + (bufb) + s0 * 512); \
    async16(Bt + (size_t)((n0_) + str1) * Kdim + (kelem) + cswz, smB + (bufb) + s1 * 512); \
  } while (0)

  // epilogue constants
  const int lcol = l & 15;
  const int rgrp = l >> 4;
  const int rr = l >> 3;
  const int c4 = (l & 7) * 4;
  // scratch in buffer-1 halves (free after K-loop): 4 waves in smA, 4 in smB
  float* ldsT = (w < 4) ? ((float*)(smA + 8192)) + w * (16 * 36)
                        : ((float*)(smB + 8192)) + (w - 4) * (16 * 36);

  for (int nl = 0; nl < 4; ++nl) {
    const int ntile = sup * 4 + nl;
    const int n0 = ntile * BN;

    f32x4 acc[4][2];
#pragma unroll
    for (int i = 0; i < 4; ++i)
#pragma unroll
      for (int j = 0; j < 2; ++j) acc[i][j] = (f32x4){0.f, 0.f, 0.f, 0.f};

    if (nl == 0) {
      STAGE1(n0, 0, 0);
      __syncthreads();
    }
    // K-loop: starts on buf0 every tile (nIter even)
    int cur = 0;
    for (int it = 0; it < nIter; ++it) {
      if (it + 1 < nIter) STAGE1(n0, (it + 1) * BK, (cur ^ 1) * 8192);
      const int cbase = cur * 8192;
#pragma unroll
      for (int ks = 0; ks < 2; ++ks) {
        short8 af[4], bf[2];
        const int lrow = l & 15;
        const int kb = ks * 64 + ((l >> 4) << 4);
#pragma unroll
        for (int mi = 0; mi < 4; ++mi) {
          int row = wr * 64 + mi * 16 + lrow;
          int addr = row * 128 + (kb ^ ((row & 7) << 4));
          af[mi] = *(const short8*)(smA + cbase + (addr >> 1));
        }
#pragma unroll
        for (int ni = 0; ni < 2; ++ni) {
          int row = wc * 32 + ni * 16 + lrow;
          int addr = row * 128 + (kb ^ ((row & 7) << 4));
          bf[ni] = *(const short8*)(smB + cbase + (addr >> 1));
        }
#pragma unroll
        for (int mi = 0; mi < 4; ++mi)
#pragma unroll
          for (int ni = 0; ni < 2; ++ni)
            acc[mi][ni] = __builtin_amdgcn_mfma_f32_16x16x32_bf16(
                bf[ni], af[mi], acc[mi][ni], 0, 0, 0);
      }
      __syncthreads();
      cur ^= 1;
    }
    // both buffers consumed; cur == 0. Issue next tile's first staging NOW:
    // its HBM latency hides under the epilogue below.
    if (nl < 3) STAGE1(n0 + BN, 0, 0);

    // epilogue (scratch in buf1 halves; does not touch buf0)
    const int slot = ntile * 4 + wc;
#pragma unroll
    for (int mi = 0; mi < 4; ++mi) {
      int grow = m0 + wr * 64 + mi * 16 + lcol;
      float zq = a_sq[grow];
#pragma unroll
      for (int ni = 0; ni < 2; ++ni) {
        int ncol = n0 + wc * 32 + ni * 16 + rgrp * 4;
        f32x4 eqv = *(const f32x4*)(b_sq + ncol);
        f32x4 simv;
#pragma unroll
        for (int r = 0; r < 4; ++r) {
          float dist2 = fmaxf(zq + eqv[r] - 2.0f * acc[mi][ni][r], 0.0f);
          simv[r] = __expf(-0.5f * dist2);
        }
        *(f32x4*)(ldsT + lcol * 36 + ni * 16 + rgrp * 4) = simv;
      }
      asm volatile("s_waitcnt lgkmcnt(0)" ::: "memory");
#pragma unroll
      for (int pass = 0; pass < 2; ++pass) {
        int rrow = pass * 8 + rr;
        f32x4 sv = *(const f32x4*)(ldsT + rrow * 36 + c4);
        int growr = m0 + wr * 64 + mi * 16 + rrow;
        size_t gbase = (size_t)growr * ldo + (n0 + wc * 32 + c4);
        __builtin_nontemporal_store(sv, (f32x4*)(out + gbase));
        f32x4 es;
#pragma unroll
        for (int r = 0; r < 4; ++r) es[r] = __expf(sv[r]);
        u16x4 wv;
        wv.x = f32_to_bf16(es[0]); wv.y = f32_to_bf16(es[1]);
        wv.z = f32_to_bf16(es[2]); wv.w = f32_to_bf16(es[3]);
        *(u16x4*)(wb + gbase) = wv;
        float p = es[0] + es[1] + es[2] + es[3];
        p += __shfl_xor(p, 1, 64);
        p += __shfl_xor(p, 2, 64);
        p += __shfl_xor(p, 4, 64);
        if ((l & 7) == 0) rs_part[(size_t)slot * M_TOK + growr] = p;
      }
    }
    __syncthreads();   // staging landed (vmcnt0) + scratch reads done
  }
#undef STAGE1
}

// ---- gemm_bt: r14 kernel (GEMM2 with integrated reduce + fallbacks) -------
template <int EPI>
__global__ __launch_bounds__(512, 4) void gemm_bt(const u16* __restrict__ A,
                                                  const u16* __restrict__ Bt,
                                                  int Mdim, int Ndim, int Kdim,
                                                  float* __restrict__ out, int ldo,
                                                  const float* __restrict__ a_sq,
                                                  const float* __restrict__ b_sq,
                                                  float* __restrict__ rs_part,
                                                  u16* __restrict__ wb,
                                                  const float* __restrict__ scale) {
  constexpr int BM = 128, BN = 128, BK = 64;
  __shared__ __align__(16) u16 smA[2 * BM * BK];
  __shared__ __align__(16) u16 smB[2 * BN * BK];
  __shared__ float inv_rs[BM];

  const int wg = blockIdx.x;
  int m0, n0, ntile = 0;
  if (EPI == 1) {
    const int xcd = wg & 7;
    const int idx = wg >> 3;
    const int sup = idx >> 5;
    const int mloc = (idx & 31) >> 2;
    const int nloc = idx & 3;
    m0 = (xcd * 8 + mloc) * BM;
    ntile = sup * 4 + nloc;
    n0 = ntile * BN;
  } else {
    const int nTilesN = Ndim / BN;
    const int nwg = (Mdim / BM) * nTilesN;
    const int cpx = nwg >> 3;
    const int swz = (wg & 7) * cpx + (wg >> 3);
    m0 = (swz / nTilesN) * BM;
    n0 = (swz % nTilesN) * BN;
  }

  const int t = threadIdx.x;
  const int l = t & 63;
  const int w = t >> 6;
  const int wr = w >> 2;
  const int wc = w & 3;
  const int lr8 = l >> 3;
  const int cswz = (((l & 7) ^ lr8) << 3);
  const int s0 = w * 2, s1 = w * 2 + 1;
  const int str0 = s0 * 8 + lr8, str1 = s1 * 8 + lr8;

  f32x4 acc[4][2];
#pragma unroll
  for (int i = 0; i < 4; ++i)
#pragma unroll
    for (int j = 0; j < 2; ++j) acc[i][j] = (f32x4){0.f, 0.f, 0.f, 0.f};

  const int nIter = Kdim / BK;
  async16(A + (size_t)(m0 + str0) * Kdim + cswz, smA + s0 * 512);
  async16(A + (size_t)(m0 + str1) * Kdim + cswz, smA + s1 * 512);
  async16(Bt + (size_t)(n0 + str0) * Kdim + cswz, smB + s0 * 512);
  async16(Bt + (size_t)(n0 + str1) * Kdim + cswz, smB + s1 * 512);

  if (EPI == 0 && rs_part != nullptr) {
    const int rrow = t >> 2;
    const int q = t & 3;
    float s = 0.f;
#pragma unroll 8
    for (int j = q * 32; j < q * 32 + 32; ++j)
      s += rs_part[(size_t)j * M_TOK + m0 + rrow];
    s += __shfl_xor(s, 1, 64);
    s += __shfl_xor(s, 2, 64);
    if (q == 0) inv_rs[rrow] = 1.0f / s;
  }
  __syncthreads();

  int cur = 0;
  for (int it = 0; it < nIter; ++it) {
    if (it + 1 < nIter) {
      const int k0 = (it + 1) * BK;
      const int nb = (cur ^ 1) * 8192;
      async16(A + (size_t)(m0 + str0) * Kdim + k0 + cswz, smA + nb + s0 * 512);
      async16(A + (size_t)(m0 + str1) * Kdim + k0 + cswz, smA + nb + s1 * 512);
      async16(Bt + (size_t)(n0 + str0) * Kdim + k0 + cswz, smB + nb + s0 * 512);
      async16(Bt + (size_t)(n0 + str1) * Kdim + k0 + cswz, smB + nb + s1 * 512);
    }
    const int cbase = cur * 8192;
#pragma unroll
    for (int ks = 0; ks < 2; ++ks) {
      short8 af[4], bf[2];
      const int lrow = l & 15;
      const int kb = ks * 64 + ((l >> 4) << 4);
#pragma unroll
      for (int mi = 0; mi < 4; ++mi) {
        int row = wr * 64 + mi * 16 + lrow;
        int addr = row * 128 + (kb ^ ((row & 7) << 4));
        af[mi] = *(const short8*)(smA + cbase + (addr >> 1));
      }
#pragma unroll
      for (int ni = 0; ni < 2; ++ni) {
        int row = wc * 32 + ni * 16 + lrow;
        int addr = row * 128 + (kb ^ ((row & 7) << 4));
        bf[ni] = *(const short8*)(smB + cbase + (addr >> 1));
      }
#pragma unroll
      for (int mi = 0; mi < 4; ++mi)
#pragma unroll
        for (int ni = 0; ni < 2; ++ni)
          acc[mi][ni] = __builtin_amdgcn_mfma_f32_16x16x32_bf16(
              bf[ni], af[mi], acc[mi][ni], 0, 0, 0);
    }
    __syncthreads();
    cur ^= 1;
  }

  const int lcol = l & 15;
  const int rgrp = l >> 4;
  if (EPI == 1) {
    float* ldsT = ((float*)smA) + w * (16 * 36);
    const int rr = l >> 3;
    const int c4 = (l & 7) * 4;
    const int slot = ntile * 4 + wc;
#pragma unroll
    for (int mi = 0; mi < 4; ++mi) {
      int grow = m0 + wr * 64 + mi * 16 + lcol;
      float zq = a_sq[grow];
#pragma unroll
      for (int ni = 0; ni < 2; ++ni) {
        int ncol = n0 + wc * 32 + ni * 16 + rgrp * 4;
        f32x4 eqv = *(const f32x4*)(b_sq + ncol);
        f32x4 simv;
#pragma unroll
        for (int r = 0; r < 4; ++r) {
          float dist2 = fmaxf(zq + eqv[r] - 2.0f * acc[mi][ni][r], 0.0f);
          simv[r] = __expf(-0.5f * dist2);
        }
        *(f32x4*)(ldsT + lcol * 36 + ni * 16 + rgrp * 4) = simv;
      }
      asm volatile("s_waitcnt lgkmcnt(0)" ::: "memory");
#pragma unroll
      for (int pass = 0; pass < 2; ++pass) {
        int rrow = pass * 8 + rr;
        f32x4 sv = *(const f32x4*)(ldsT + rrow * 36 + c4);
        int growr = m0 + wr * 64 + mi * 16 + rrow;
        size_t gbase = (size_t)growr * ldo + (n0 + wc * 32 + c4);
        __builtin_nontemporal_store(sv, (f32x4*)(out + gbase));
        f32x4 es;
#pragma unroll
        for (int r = 0; r < 4; ++r) es[r] = __expf(sv[r]);
        if (wb) {
          u16x4 wv;
          wv.x = f32_to_bf16(es[0]); wv.y = f32_to_bf16(es[1]);
          wv.z = f32_to_bf16(es[2]); wv.w = f32_to_bf16(es[3]);
          *(u16x4*)(wb + gbase) = wv;
        }
        float p = es[0] + es[1] + es[2] + es[3];
        p += __shfl_xor(p, 1, 64);
        p += __shfl_xor(p, 2, 64);
        p += __shfl_xor(p, 4, 64);
        if ((l & 7) == 0) rs_part[(size_t)slot * M_TOK + growr] = p;
      }
    }
  } else {
#pragma unroll
    for (int mi = 0; mi < 4; ++mi) {
      int grow = m0 + wr * 64 + mi * 16 + lcol;
      float s;
      if (rs_part != nullptr)      s = inv_rs[wr * 64 + mi * 16 + lcol];
      else if (scale != nullptr)   s = 1.0f / scale[grow];
      else                         s = 1.0f;
#pragma unroll
      for (int ni = 0; ni < 2; ++ni) {
        int ncol = n0 + wc * 32 + ni * 16 + rgrp * 4;
        f32x4 v = acc[mi][ni] * s;
        *(f32x4*)(out + (size_t)grow * ldo + ncol) = v;
      }
    }
  }
}

// ---- weights (fallback path only) -----------------------------------------
__global__ __launch_bounds__(256) void weights_kernel(const float* __restrict__ sim,
                                                      const float* __restrict__ rowsum,
                                                      u16* __restrict__ wb) {
  size_t i = ((size_t)blockIdx.x * 256 + threadIdx.x) * 8;
  int row = (int)(i >> 12);
  float inv = 1.0f / rowsum[row];
  float4 a = *(const float4*)(sim + i);
  float4 b = *(const float4*)(sim + i + 4);
  u32 w0 = (u32)f32_to_bf16(__expf(a.x) * inv) | ((u32)f32_to_bf16(__expf(a.y) * inv) << 16);
  u32 w1 = (u32)f32_to_bf16(__expf(a.z) * inv) | ((u32)f32_to_bf16(__expf(a.w) * inv) << 16);
  u32 w2 = (u32)f32_to_bf16(__expf(b.x) * inv) | ((u32)f32_to_bf16(__expf(b.y) * inv) << 16);
  u32 w3 = (u32)f32_to_bf16(__expf(b.z) * inv) | ((u32)f32_to_bf16(__expf(b.w) * inv) << 16);
  uint4 o; o.x = w0; o.y = w1; o.z = w2; o.w = w3;
  *(uint4*)(wb + i) = o;
}

extern "C" void kernel_launch(void* const* d_in, const int* in_sizes, int n_in,
                              void* d_out, int out_size, void* d_ws, size_t ws_size,
                              hipStream_t stream) {
  const float* z = (const float*)d_in[0];
  const float* e = (const float*)d_in[1];
  float* out = (float*)d_out;
  float* sim = out;                                   // [8192,4096]
  float* wout = out + (size_t)M_TOK * N_EXP;          // [8192,1024]

  char* ws = (char*)d_ws;
  const size_t MB = (size_t)1 << 20;
  const bool fused = ws_size >= 100 * MB + 96 * 1024;

  if (fused) {
    u16* zb  = (u16*)ws;                              // 16 MiB
    u16* eb  = (u16*)(ws + 16 * MB);                  // 8 MiB
    u16* ebT = (u16*)(ws + 24 * MB);                  // 8 MiB
    u16* Wb  = (u16*)(ws + 32 * MB);                  // 64 MiB
    float* rs_part = (float*)(ws + 96 * MB);          // 4 MiB (128 x 8192)
    float* z_sq   = (float*)(ws + 100 * MB);
    float* e_sq   = (float*)(ws + 100 * MB + 32768);

    prep_convert2<<<M_TOK + N_EXP, 256, 0, stream>>>(z, e, zb, eb, z_sq, e_sq);
    transpose_bf16<<<dim3(N_EXP / 64, D_DIM / 64), 256, 0, stream>>>(eb, ebT);

    // GEMM1 (persistent, 512 blocks x 4 tiles): sim -> out (nt),
    // bf16(exp(sim)) -> Wb, partial rowsums -> rs_part
    gemm1_persist<<<512, 512, 0, stream>>>(zb, eb, sim, z_sq, e_sq, rs_part, Wb);

    // GEMM2: wout = (Wb @ E) / rowsum; rowsum reduced in-kernel from rs_part
    gemm_bt<0><<<(M_TOK / 128) * (D_DIM / 128), 512, 0, stream>>>(
        Wb, ebT, M_TOK, D_DIM, N_EXP, wout, D_DIM, nullptr, nullptr, rs_part,
        nullptr, nullptr);
  } else {
    // fallback: zb aliases Wb, separate weights pass (round-9 style)
    u16* Wb  = (u16*)ws;                              // 64 MiB
    u16* zb  = (u16*)ws;                              // aliases Wb
    u16* eb  = (u16*)(ws + 64 * MB);                  // 8 MiB
    u16* ebT = (u16*)(ws + 72 * MB);                  // 8 MiB
    float* rs_part = (float*)(ws + 80 * MB);          // 4 MiB
    float* z_sq   = (float*)(ws + 84 * MB);
    float* e_sq   = (float*)(ws + 84 * MB + 32768);
    float* rowsum = (float*)(ws + 84 * MB + 49152);

    prep_convert2<<<M_TOK + N_EXP, 256, 0, stream>>>(z, e, zb, eb, z_sq, e_sq);
    transpose_bf16<<<dim3(N_EXP / 64, D_DIM / 64), 256, 0, stream>>>(eb, ebT);

    gemm_bt<1><<<(M_TOK / 128) * (N_EXP / 128), 512, 0, stream>>>(
        zb, eb, M_TOK, N_EXP, D_DIM, sim, N_EXP, z_sq, e_sq, rs_part,
        nullptr, nullptr);

    rowsum_reduce<<<M_TOK / 256, 256, 0, stream>>>(rs_part, rowsum);

    weights_kernel<<<(M_TOK * (size_t)N_EXP) / (8 * 256), 256, 0, stream>>>(sim, rowsum, Wb);

    gemm_bt<0><<<(M_TOK / 128) * (D_DIM / 128), 512, 0, stream>>>(
        Wb, ebT, M_TOK, D_DIM, N_EXP, wout, D_DIM, nullptr, nullptr, nullptr,
        nullptr, nullptr);
  }
}

// Round 16
// 187.961 us; speedup vs baseline: 1.1503x; 1.1503x over previous
//
#include <hip/hip_runtime.h>
#include <stdint.h>

// GaussianKernelSimilarity: z[8192,1024] f32, expert_keys[4096,1024] f32
// out0 = exp(-max(|z|^2+|e|^2-2 z.e, 0)/2)  [8192,4096]
// out1 = softmax(out0, axis=-1) @ expert_keys [8192,1024]
//
// Round 16: REVERT to the round-14 configuration (best measured: 188.3,
// tied with r9's 187.9). r15's persistent GEMM1 refuted the per-block-
// overhead theory (drift broke L2 super-tile locality: FETCH 66->160 MB).
// Structure: prep (fused z+e convert + |.|^2) -> transpose(e) ->
// GEMM1 (128x128, BK=64, 8 waves, XOR-swizzled LDS, L2-aware XCD
// super-tiles, LDS-transpose exp-once epilogue, nt sim stores, Wb store,
// no-atomic partial rowsums) -> GEMM2 (same K-loop, K=4096, rowsum
// reduced from rs_part in its prologue, scaled epilogue).

#define M_TOK 8192
#define N_EXP 4096
#define D_DIM 1024

typedef __attribute__((ext_vector_type(4))) float f32x4;
typedef __attribute__((ext_vector_type(8))) short short8;
typedef __attribute__((ext_vector_type(4))) unsigned short u16x4;
typedef unsigned short u16;
typedef unsigned int u32;

__device__ __forceinline__ u16 f32_to_bf16(float f) {
  u32 u = __builtin_bit_cast(u32, f);
  u += 0x7fff + ((u >> 16) & 1);   // round-to-nearest-even
  return (u16)(u >> 16);
}

__device__ __forceinline__ void async16(const void* g, void* l) {
  __builtin_amdgcn_global_load_lds((__attribute__((address_space(1))) void*)(g),
                                   (__attribute__((address_space(3))) void*)(l),
                                   16, 0, 0);
}

// ---- prep: f32 -> bf16 convert + row |.|^2 for BOTH z and e (one launch) --
__global__ __launch_bounds__(256) void prep_convert2(const float* __restrict__ zsrc,
                                                     const float* __restrict__ esrc,
                                                     u16* __restrict__ zdst,
                                                     u16* __restrict__ edst,
                                                     float* __restrict__ zsq,
                                                     float* __restrict__ esq) {
  int row = blockIdx.x;
  const float* src;
  u16* dst;
  float* sq;
  if (row < M_TOK) {
    src = zsrc + (size_t)row * D_DIM;
    dst = zdst + (size_t)row * D_DIM;
    sq = zsq + row;
  } else {
    int r = row - M_TOK;
    src = esrc + (size_t)r * D_DIM;
    dst = edst + (size_t)r * D_DIM;
    sq = esq + r;
  }
  int t = threadIdx.x;                       // 256 threads, 4 elems each
  const float4 v = ((const float4*)src)[t];
  ushort4 h;
  h.x = f32_to_bf16(v.x); h.y = f32_to_bf16(v.y);
  h.z = f32_to_bf16(v.z); h.w = f32_to_bf16(v.w);
  ((ushort4*)dst)[t] = h;
  float p = v.x * v.x + v.y * v.y + v.z * v.z + v.w * v.w;
#pragma unroll
  for (int off = 1; off < 64; off <<= 1) p += __shfl_xor(p, off, 64);
  __shared__ float partial[4];
  if ((t & 63) == 0) partial[t >> 6] = p;
  __syncthreads();
  if (t == 0) *sq = partial[0] + partial[1] + partial[2] + partial[3];
}

// ---- bf16 transpose: eb[4096][1024] -> ebT[1024][4096] --------------------
__global__ __launch_bounds__(256) void transpose_bf16(const u16* __restrict__ src,
                                                      u16* __restrict__ dst) {
  __shared__ u16 tile[64][65];
  int e0 = blockIdx.x * 64;
  int d0 = blockIdx.y * 64;
  int t = threadIdx.x;
  int lr = t >> 4;
  int lc = (t & 15) * 4;
#pragma unroll
  for (int r8 = 0; r8 < 4; ++r8) {
    int row = lr + r8 * 16;
    ushort4 v = *(const ushort4*)(src + (size_t)(e0 + row) * D_DIM + d0 + lc);
    tile[row][lc + 0] = v.x; tile[row][lc + 1] = v.y;
    tile[row][lc + 2] = v.z; tile[row][lc + 3] = v.w;
  }
  __syncthreads();
#pragma unroll
  for (int r8 = 0; r8 < 4; ++r8) {
    int dl = lr + r8 * 16;
    ushort4 v;
    v.x = tile[lc + 0][dl]; v.y = tile[lc + 1][dl];
    v.z = tile[lc + 2][dl]; v.w = tile[lc + 3][dl];
    *(ushort4*)(dst + (size_t)(d0 + dl) * N_EXP + e0 + lc) = v;
  }
}

// ---- rowsum reduce (fallback path only) -----------------------------------
__global__ __launch_bounds__(256) void rowsum_reduce(const float* __restrict__ part,
                                                     float* __restrict__ rowsum) {
  int r = blockIdx.x * 256 + threadIdx.x;
  float s = 0.f;
#pragma unroll 8
  for (int j = 0; j < 128; ++j) s += part[(size_t)j * M_TOK + r];
  rowsum[r] = s;
}

// ---- gemm_bt: round-9 kernel + integrated rowsum reduce in EPI=0 ----------
// 128x128 tile, BK=64, 512 threads = 8 waves (2M x 4N), dbuf 64 KiB.
// LDS XOR-swizzle on read, pre-swizzled global source for global_load_lds.
// SWAPPED operands mfma(bf, af, acc):
//   m-row = lane&15 (+mi*16+wr*64), n-col = (lane>>4)*4+reg (+ni*16+wc*32)
// EPI=1: XCD stripe + 8m x 4n super-tiles; LDS-transposed full-line sim
//   stores (nt); es=exp(sim) once -> Wb + partial rowsum rs_part[slot][row].
// EPI=0: XCD chunk swizzle; if rs_part non-null: cooperative 128-partial
//   reduce into inv_rs[] LDS during prologue (hides under staging latency),
//   epilogue scales by inv_rs; else scales by 1/scale[row] (or 1).
template <int EPI>
__global__ __launch_bounds__(512, 4) void gemm_bt(const u16* __restrict__ A,
                                                  const u16* __restrict__ Bt,
                                                  int Mdim, int Ndim, int Kdim,
                                                  float* __restrict__ out, int ldo,
                                                  const float* __restrict__ a_sq,
                                                  const float* __restrict__ b_sq,
                                                  float* __restrict__ rs_part,
                                                  u16* __restrict__ wb,
                                                  const float* __restrict__ scale) {
  constexpr int BM = 128, BN = 128, BK = 64;
  __shared__ __align__(16) u16 smA[2 * BM * BK];   // 32 KiB
  __shared__ __align__(16) u16 smB[2 * BN * BK];   // 32 KiB
  __shared__ float inv_rs[BM];                     // 512 B (EPI=0 integrated)

  const int wg = blockIdx.x;
  int m0, n0, ntile = 0;
  if (EPI == 1) {
    const int xcd = wg & 7;
    const int idx = wg >> 3;
    const int sup = idx >> 5;
    const int mloc = (idx & 31) >> 2;
    const int nloc = idx & 3;
    m0 = (xcd * 8 + mloc) * BM;
    ntile = sup * 4 + nloc;
    n0 = ntile * BN;
  } else {
    const int nTilesN = Ndim / BN;
    const int nwg = (Mdim / BM) * nTilesN;
    const int cpx = nwg >> 3;
    const int swz = (wg & 7) * cpx + (wg >> 3);
    m0 = (swz / nTilesN) * BM;
    n0 = (swz % nTilesN) * BN;
  }

  const int t = threadIdx.x;
  const int l = t & 63;
  const int w = t >> 6;          // wave 0..7
  const int wr = w >> 2;         // 0..1 (M)
  const int wc = w & 3;          // 0..3 (N)
  const int lr8 = l >> 3;
  const int cswz = (((l & 7) ^ lr8) << 3);
  const int s0 = w * 2, s1 = w * 2 + 1;
  const int str0 = s0 * 8 + lr8, str1 = s1 * 8 + lr8;

  f32x4 acc[4][2];
#pragma unroll
  for (int i = 0; i < 4; ++i)
#pragma unroll
    for (int j = 0; j < 2; ++j) acc[i][j] = (f32x4){0.f, 0.f, 0.f, 0.f};

  const int nIter = Kdim / BK;
  async16(A + (size_t)(m0 + str0) * Kdim + cswz, smA + s0 * 512);
  async16(A + (size_t)(m0 + str1) * Kdim + cswz, smA + s1 * 512);
  async16(Bt + (size_t)(n0 + str0) * Kdim + cswz, smB + s0 * 512);
  async16(Bt + (size_t)(n0 + str1) * Kdim + cswz, smB + s1 * 512);

  if (EPI == 0 && rs_part != nullptr) {
    // integrated rowsum reduce for this block's 128 rows, hidden under the
    // prologue staging latency. 4 threads per row, 32 partials each.
    const int rrow = t >> 2;          // 0..127
    const int q = t & 3;              // partial quarter
    float s = 0.f;
#pragma unroll 8
    for (int j = q * 32; j < q * 32 + 32; ++j)
      s += rs_part[(size_t)j * M_TOK + m0 + rrow];
    s += __shfl_xor(s, 1, 64);
    s += __shfl_xor(s, 2, 64);
    if (q == 0) inv_rs[rrow] = 1.0f / s;
  }
  __syncthreads();

  int cur = 0;
  for (int it = 0; it < nIter; ++it) {
    if (it + 1 < nIter) {
      const int k0 = (it + 1) * BK;
      const int nb = (cur ^ 1) * 8192;
      async16(A + (size_t)(m0 + str0) * Kdim + k0 + cswz, smA + nb + s0 * 512);
      async16(A + (size_t)(m0 + str1) * Kdim + k0 + cswz, smA + nb + s1 * 512);
      async16(Bt + (size_t)(n0 + str0) * Kdim + k0 + cswz, smB + nb + s0 * 512);
      async16(Bt + (size_t)(n0 + str1) * Kdim + k0 + cswz, smB + nb + s1 * 512);
    }
    const int cbase = cur * 8192;
#pragma unroll
    for (int ks = 0; ks < 2; ++ks) {
      short8 af[4], bf[2];
      const int lrow = l & 15;
      const int kb = ks * 64 + ((l >> 4) << 4);
#pragma unroll
      for (int mi = 0; mi < 4; ++mi) {
        int row = wr * 64 + mi * 16 + lrow;
        int addr = row * 128 + (kb ^ ((row & 7) << 4));
        af[mi] = *(const short8*)(smA + cbase + (addr >> 1));
      }
#pragma unroll
      for (int ni = 0; ni < 2; ++ni) {
        int row = wc * 32 + ni * 16 + lrow;
        int addr = row * 128 + (kb ^ ((row & 7) << 4));
        bf[ni] = *(const short8*)(smB + cbase + (addr >> 1));
      }
#pragma unroll
      for (int mi = 0; mi < 4; ++mi)
#pragma unroll
        for (int ni = 0; ni < 2; ++ni)
          acc[mi][ni] = __builtin_amdgcn_mfma_f32_16x16x32_bf16(
              bf[ni], af[mi], acc[mi][ni], 0, 0, 0);
    }
    __syncthreads();
    cur ^= 1;
  }

  const int lcol = l & 15;
  const int rgrp = l >> 4;
  if (EPI == 1) {
    float* ldsT = ((float*)smA) + w * (16 * 36);   // wave-private scratch
    const int rr = l >> 3;
    const int c4 = (l & 7) * 4;
    const int slot = ntile * 4 + wc;
#pragma unroll
    for (int mi = 0; mi < 4; ++mi) {
      int grow = m0 + wr * 64 + mi * 16 + lcol;
      float zq = a_sq[grow];
#pragma unroll
      for (int ni = 0; ni < 2; ++ni) {
        int ncol = n0 + wc * 32 + ni * 16 + rgrp * 4;
        f32x4 eqv = *(const f32x4*)(b_sq + ncol);
        f32x4 simv;
#pragma unroll
        for (int r = 0; r < 4; ++r) {
          float dist2 = fmaxf(zq + eqv[r] - 2.0f * acc[mi][ni][r], 0.0f);
          simv[r] = __expf(-0.5f * dist2);
        }
        *(f32x4*)(ldsT + lcol * 36 + ni * 16 + rgrp * 4) = simv;
      }
      asm volatile("s_waitcnt lgkmcnt(0)" ::: "memory");
#pragma unroll
      for (int pass = 0; pass < 2; ++pass) {
        int rrow = pass * 8 + rr;
        f32x4 sv = *(const f32x4*)(ldsT + rrow * 36 + c4);
        int growr = m0 + wr * 64 + mi * 16 + rrow;
        size_t gbase = (size_t)growr * ldo + (n0 + wc * 32 + c4);
        __builtin_nontemporal_store(sv, (f32x4*)(out + gbase));
        f32x4 es;
#pragma unroll
        for (int r = 0; r < 4; ++r) es[r] = __expf(sv[r]);
        if (wb) {
          u16x4 wv;
          wv.x = f32_to_bf16(es[0]); wv.y = f32_to_bf16(es[1]);
          wv.z = f32_to_bf16(es[2]); wv.w = f32_to_bf16(es[3]);
          *(u16x4*)(wb + gbase) = wv;
        }
        float p = es[0] + es[1] + es[2] + es[3];
        p += __shfl_xor(p, 1, 64);
        p += __shfl_xor(p, 2, 64);
        p += __shfl_xor(p, 4, 64);
        if ((l & 7) == 0) rs_part[(size_t)slot * M_TOK + growr] = p;
      }
    }
  } else {
#pragma unroll
    for (int mi = 0; mi < 4; ++mi) {
      int grow = m0 + wr * 64 + mi * 16 + lcol;
      float s;
      if (rs_part != nullptr)      s = inv_rs[wr * 64 + mi * 16 + lcol];
      else if (scale != nullptr)   s = 1.0f / scale[grow];
      else                         s = 1.0f;
#pragma unroll
      for (int ni = 0; ni < 2; ++ni) {
        int ncol = n0 + wc * 32 + ni * 16 + rgrp * 4;
        f32x4 v = acc[mi][ni] * s;
        *(f32x4*)(out + (size_t)grow * ldo + ncol) = v;
      }
    }
  }
}

// ---- weights (fallback path only) -----------------------------------------
__global__ __launch_bounds__(256) void weights_kernel(const float* __restrict__ sim,
                                                      const float* __restrict__ rowsum,
                                                      u16* __restrict__ wb) {
  size_t i = ((size_t)blockIdx.x * 256 + threadIdx.x) * 8;
  int row = (int)(i >> 12);
  float inv = 1.0f / rowsum[row];
  float4 a = *(const float4*)(sim + i);
  float4 b = *(const float4*)(sim + i + 4);
  u32 w0 = (u32)f32_to_bf16(__expf(a.x) * inv) | ((u32)f32_to_bf16(__expf(a.y) * inv) << 16);
  u32 w1 = (u32)f32_to_bf16(__expf(a.z) * inv) | ((u32)f32_to_bf16(__expf(a.w) * inv) << 16);
  u32 w2 = (u32)f32_to_bf16(__expf(b.x) * inv) | ((u32)f32_to_bf16(__expf(b.y) * inv) << 16);
  u32 w3 = (u32)f32_to_bf16(__expf(b.z) * inv) | ((u32)f32_to_bf16(__expf(b.w) * inv) << 16);
  uint4 o; o.x = w0; o.y = w1; o.z = w2; o.w = w3;
  *(uint4*)(wb + i) = o;
}

extern "C" void kernel_launch(void* const* d_in, const int* in_sizes, int n_in,
                              void* d_out, int out_size, void* d_ws, size_t ws_size,
                              hipStream_t stream) {
  const float* z = (const float*)d_in[0];
  const float* e = (const float*)d_in[1];
  float* out = (float*)d_out;
  float* sim = out;                                   // [8192,4096]
  float* wout = out + (size_t)M_TOK * N_EXP;          // [8192,1024]

  char* ws = (char*)d_ws;
  const size_t MB = (size_t)1 << 20;
  const bool fused = ws_size >= 100 * MB + 96 * 1024;

  if (fused) {
    u16* zb  = (u16*)ws;                              // 16 MiB
    u16* eb  = (u16*)(ws + 16 * MB);                  // 8 MiB
    u16* ebT = (u16*)(ws + 24 * MB);                  // 8 MiB
    u16* Wb  = (u16*)(ws + 32 * MB);                  // 64 MiB
    float* rs_part = (float*)(ws + 96 * MB);          // 4 MiB (128 x 8192)
    float* z_sq   = (float*)(ws + 100 * MB);
    float* e_sq   = (float*)(ws + 100 * MB + 32768);

    prep_convert2<<<M_TOK + N_EXP, 256, 0, stream>>>(z, e, zb, eb, z_sq, e_sq);
    transpose_bf16<<<dim3(N_EXP / 64, D_DIM / 64), 256, 0, stream>>>(eb, ebT);

    // GEMM1: sim -> out (nt), bf16(exp(sim)) -> Wb, partial rowsums
    gemm_bt<1><<<(M_TOK / 128) * (N_EXP / 128), 512, 0, stream>>>(
        zb, eb, M_TOK, N_EXP, D_DIM, sim, N_EXP, z_sq, e_sq, rs_part, Wb, nullptr);

    // GEMM2: wout = (Wb @ E) / rowsum; rowsum reduced in-kernel from rs_part
    gemm_bt<0><<<(M_TOK / 128) * (D_DIM / 128), 512, 0, stream>>>(
        Wb, ebT, M_TOK, D_DIM, N_EXP, wout, D_DIM, nullptr, nullptr, rs_part,
        nullptr, nullptr);
  } else {
    // fallback: zb aliases Wb, separate weights pass (round-9 style)
    u16* Wb  = (u16*)ws;                              // 64 MiB
    u16* zb  = (u16*)ws;                              // aliases Wb
    u16* eb  = (u16*)(ws + 64 * MB);                  // 8 MiB
    u16* ebT = (u16*)(ws + 72 * MB);                  // 8 MiB
    float* rs_part = (float*)(ws + 80 * MB);          // 4 MiB
    float* z_sq   = (float*)(ws + 84 * MB);
    float* e_sq   = (float*)(ws + 84 * MB + 32768);
    float* rowsum = (float*)(ws + 84 * MB + 49152);

    prep_convert2<<<M_TOK + N_EXP, 256, 0, stream>>>(z, e, zb, eb, z_sq, e_sq);
    transpose_bf16<<<dim3(N_EXP / 64, D_DIM / 64), 256, 0, stream>>>(eb, ebT);

    gemm_bt<1><<<(M_TOK / 128) * (N_EXP / 128), 512, 0, stream>>>(
        zb, eb, M_TOK, N_EXP, D_DIM, sim, N_EXP, z_sq, e_sq, rs_part,
        nullptr, nullptr);

    rowsum_reduce<<<M_TOK / 256, 256, 0, stream>>>(rs_part, rowsum);

    weights_kernel<<<(M_TOK * (size_t)N_EXP) / (8 * 256), 256, 0, stream>>>(sim, rowsum, Wb);

    gemm_bt<0><<<(M_TOK / 128) * (D_DIM / 128), 512, 0, stream>>>(
        Wb, ebT, M_TOK, D_DIM, N_EXP, wout, D_DIM, nullptr, nullptr, nullptr,
        nullptr, nullptr);
  }
}